// Round 10
// baseline (463.136 us; speedup 1.0000x reference)
//
#include <hip/hip_runtime.h>
#include <hip/hip_fp16.h>

#define N    8192
#define FIN  256
#define FOUT 128
#define BN   64

typedef _Float16 half8 __attribute__((ext_vector_type(8)));
typedef _Float16 half4v __attribute__((ext_vector_type(4)));
typedef float floatx4 __attribute__((ext_vector_type(4)));

// async global->LDS, 16B per lane (gfx950)
#define GLDS(g, l) __builtin_amdgcn_global_load_lds(                        \
    (const __attribute__((address_space(1))) void*)(g),                     \
    (__attribute__((address_space(3))) void*)(l), 16, 0, 0)

// ---------------------------------------------------------------------------
// W-prep: frag-major fp16 W for coalesced MFMA B-loads.
// ---------------------------------------------------------------------------
__global__ __launch_bounds__(256)
void wprep_kernel(const float* __restrict__ W0,
                  const float* __restrict__ W1,
                  const float* __restrict__ W2,
                  _Float16* __restrict__ Wf)
{
    int idx  = blockIdx.x * 256 + threadIdx.x;   // 0..12287
    int lane = idx & 63;
    int frag = idx >> 6;
    int w    = frag >> 6;
    int f    = frag & 63;
    int nt   = f >> 3, kc = f & 7;
    int quad = lane >> 4, lo16 = lane & 15;
    const float* Wp = w == 0 ? W0 : (w == 1 ? W1 : W2);
    half8 v;
#pragma unroll
    for (int jj = 0; jj < 8; jj++)
        v[jj] = (_Float16)Wp[(size_t)(kc * 32 + quad * 8 + jj) * FOUT + nt * 16 + lo16];
    *(half8*)&Wf[(size_t)idx * 8] = v;
}

// ---------------------------------------------------------------------------
// H = fp16(inp@W), H2 = fp16(inp@W2), H3T = fp16((inp@W3)^T). Barrier-free.
// ---------------------------------------------------------------------------
__global__ __launch_bounds__(256, 2)
void gemm3_kernel(const float* __restrict__ inp,
                  const _Float16* __restrict__ Wf,
                  _Float16* __restrict__ H,
                  _Float16* __restrict__ H2,
                  _Float16* __restrict__ H3T)
{
    const int which = blockIdx.z;
    const int c0    = blockIdx.y * 64;
    const _Float16* Wfw = Wf + (size_t)which * 64 * 64 * 8;
    const int r0 = blockIdx.x * 64;
    const int tid  = threadIdx.x;
    const int wave = tid >> 6;
    const int lane = tid & 63;
    const int lo16 = lane & 15;
    const int quad = lane >> 4;
    const int r = r0 + wave * 16 + lo16;

    half8 a[8];
#pragma unroll
    for (int kc = 0; kc < 8; kc++) {
        const float* p = &inp[(size_t)r * FIN + kc * 32 + quad * 8];
        float4 v0 = *(const float4*)p;
        float4 v1 = *(const float4*)(p + 4);
        a[kc][0] = (_Float16)v0.x; a[kc][1] = (_Float16)v0.y;
        a[kc][2] = (_Float16)v0.z; a[kc][3] = (_Float16)v0.w;
        a[kc][4] = (_Float16)v1.x; a[kc][5] = (_Float16)v1.y;
        a[kc][6] = (_Float16)v1.z; a[kc][7] = (_Float16)v1.w;
    }

    floatx4 acc[4];
#pragma unroll
    for (int i = 0; i < 4; i++) acc[i] = (floatx4){0.f, 0.f, 0.f, 0.f};

#pragma unroll
    for (int kc = 0; kc < 8; kc++)
#pragma unroll
        for (int nt = 0; nt < 4; nt++) {
            int ntg = (c0 >> 4) + nt;
            half8 b = *(const half8*)&Wfw[(((size_t)ntg * 8 + kc) * 64 + lane) * 8];
            acc[nt] = __builtin_amdgcn_mfma_f32_16x16x32_f16(a[kc], b, acc[nt], 0, 0, 0);
        }

    const int arow = wave * 16 + quad * 4;
    if (which < 2) {
        _Float16* outp = which == 0 ? H : H2;
#pragma unroll
        for (int nt = 0; nt < 4; nt++)
#pragma unroll
            for (int rr = 0; rr < 4; rr++)
                outp[(size_t)(r0 + arow + rr) * FOUT + c0 + nt * 16 + lo16] = (_Float16)acc[nt][rr];
    } else {
#pragma unroll
        for (int nt = 0; nt < 4; nt++) {
            half4v v;
#pragma unroll
            for (int rr = 0; rr < 4; rr++) v[rr] = (_Float16)acc[nt][rr];
            *(half4v*)&H3T[(size_t)(c0 + nt * 16 + lo16) * N + r0 + arow] = v;
        }
    }
}

// ---------------------------------------------------------------------------
// Repack K with the sigma j-permutation baked in (see R7 comment).
// Kf[jb][c(2)][ntj(2)][kc(4)][lane][8]
// ---------------------------------------------------------------------------
__global__ __launch_bounds__(256)
void repackK_kernel(const _Float16* __restrict__ H2, _Float16* __restrict__ Kf)
{
    int idx  = blockIdx.x * 256 + threadIdx.x;
    int lane = idx & 63;
    int frag = idx >> 6;
    int jb = frag >> 4, f = frag & 15;
    int c = f >> 3, ntj = (f >> 2) & 1, kc = f & 3;
    int quad = lane >> 4, lo16 = lane & 15;
    int srcrow = jb * 64 + c * 32 + (lo16 >> 2) * 8 + ntj * 4 + (lo16 & 3);
    half8 v = *(const half8*)&H2[(size_t)srcrow * FOUT + kc * 32 + quad * 8];
    *(half8*)&Kf[(size_t)idx * 8] = v;
}

// ---------------------------------------------------------------------------
// Repack V^T into frag-major (PV A-operand). Vf[jb][nt(8)][kcj(2)][lane][8]
// ---------------------------------------------------------------------------
__global__ __launch_bounds__(256)
void repackV_kernel(const _Float16* __restrict__ H3T, _Float16* __restrict__ Vf)
{
    int idx  = blockIdx.x * 256 + threadIdx.x;
    int lane = idx & 63;
    int frag = idx >> 6;
    int jb = frag >> 4, f = frag & 15, nt = f >> 1, kc = f & 1;
    int quad = lane >> 4, lo16 = lane & 15;
    half8 v = *(const half8*)&H3T[(size_t)(nt * 16 + lo16) * N + jb * 64 + kc * 32 + quad * 8];
    *(half8*)&Vf[(size_t)idx * 8] = v;
}

// ---------------------------------------------------------------------------
// Flash attention v6: BM=64 (16 i/wave) for low VGPR -> 3 blocks/CU,
// single 32KB KV buffer via global_load_lds (no staging regs, m97 2-barrier
// pattern), adjacency read as 1KB-contiguous int4 rows + ballot once per
// 4-iteration group (4 resident u64 masks per lane).
// ---------------------------------------------------------------------------
template<int JS>
__global__ __launch_bounds__(256, 3)
void attn_kernel(const _Float16* __restrict__ Hq,   // [N][128]
                 const _Float16* __restrict__ Kf,   // permuted frag-major
                 const _Float16* __restrict__ Vf,   // frag-major
                 const int* __restrict__ adj,       // [N][N]
                 float* __restrict__ OpartT,        // [JS][FOUT][N]
                 float* __restrict__ mpart,         // [JS][N]
                 float* __restrict__ lpart)         // [JS][N]
{
    __shared__ _Float16 KV[16384];   // 32 KB: 16 K frags | 16 V frags

    const int tid  = threadIdx.x;
    const int wave = tid >> 6;
    const int lane = tid & 63;
    const int lo16 = lane & 15;
    const int quad = lane >> 4;
    const int bid  = blockIdx.x;
    const int js   = bid & (JS - 1);      // XCD affinity
    const int ib   = bid / JS;
    const int i0   = ib * 64;
    const int iw   = i0 + wave * 16;
    const int jbeg = js * (N / JS);
    const int NG   = (N / JS) / (BN * 4); // 4-iteration groups

    // Q as B-operand fragments (i = lo16)
    half8 q[4];
#pragma unroll
    for (int kc = 0; kc < 4; kc++)
        q[kc] = *(const half8*)&Hq[(size_t)(iw + lo16) * FOUT + kc * 32 + quad * 8];

    floatx4 O[8];
#pragma unroll
    for (int nt = 0; nt < 8; nt++) O[nt] = (floatx4){0.f, 0.f, 0.f, 0.f};
    float m_r = -1e12f, l_r = 0.f;

    const int* abase = adj + (size_t)iw * N + jbeg + 4 * lane;

    for (int itg = 0; itg < NG; itg++) {
        // ---- adj for this 256-col group: 1KB-contiguous int4 per row,
        //      balloted into 4 resident u64s per lane (row = lo16) ----
        unsigned long long b64[4] = {0, 0, 0, 0};
#pragma unroll
        for (int half = 0; half < 2; half++) {
            int4 av[8];
#pragma unroll
            for (int x = 0; x < 8; x++)
                av[x] = *(const int4*)(abase + (size_t)(half * 8 + x) * N + itg * 256);
#pragma unroll
            for (int x = 0; x < 8; x++) {
                unsigned long long bx = __ballot(av[x].x != 0);
                unsigned long long by = __ballot(av[x].y != 0);
                unsigned long long bz = __ballot(av[x].z != 0);
                unsigned long long bw = __ballot(av[x].w != 0);
                bool sel = (lo16 == half * 8 + x);
                b64[0] = sel ? bx : b64[0];
                b64[1] = sel ? by : b64[1];
                b64[2] = sel ? bz : b64[2];
                b64[3] = sel ? bw : b64[3];
            }
        }

        #pragma unroll
        for (int w = 0; w < 4; w++) {
            const int jb = (jbeg + (itg * 4 + w) * BN) >> 6;
            const _Float16* gk = Kf + (size_t)jb * 8192;
            const _Float16* gv = Vf + (size_t)jb * 8192;
            // stage KV tile direct-to-LDS (16B/lane, wave-uniform base)
#pragma unroll
            for (int r = 0; r < 4; r++) {
                int off = (r * 256 + tid) * 8;
                GLDS(gk + off, &KV[off]);
                GLDS(gv + off, &KV[8192 + off]);
            }
            __syncthreads();   // b1: vmcnt(0) drains GLDS (+adj) for all waves

            // this window's 16-bit mask slices (bit (c*8+quad*2+ntj) of mh[r])
            unsigned int mh[4];
#pragma unroll
            for (int r = 0; r < 4; r++)
                mh[r] = (unsigned int)(b64[r] >> (w * 16)) & 0xffffu;

            // S^T = K Q^T (j = c*32 + 8*quad + 4*ntj + r, i = lo16)
            floatx4 S[2][2];
#pragma unroll
            for (int c = 0; c < 2; c++)
#pragma unroll
                for (int ntj = 0; ntj < 2; ntj++) {
                    S[c][ntj] = (floatx4){0.f, 0.f, 0.f, 0.f};
#pragma unroll
                    for (int kc = 0; kc < 4; kc++) {
                        half8 kf = *(const half8*)&KV[(((c * 2 + ntj) * 4 + kc) * 64 + lane) * 8];
                        S[c][ntj] = __builtin_amdgcn_mfma_f32_16x16x32_f16(kf, q[kc], S[c][ntj], 0, 0, 0);
                    }
                }

            // unmasked running max (LeakyReLU inline), 2-step quad butterfly
            float mx = -1e12f;
#pragma unroll
            for (int c = 0; c < 2; c++)
#pragma unroll
                for (int ntj = 0; ntj < 2; ntj++)
#pragma unroll
                    for (int r = 0; r < 4; r++) {
                        float e = S[c][ntj][r];
                        e = e > 0.f ? e : 0.2f * e;
                        mx = fmaxf(mx, e);
                    }
            mx = fmaxf(mx, __shfl_xor(mx, 16));
            mx = fmaxf(mx, __shfl_xor(mx, 32));
            float mn = fmaxf(m_r, mx);
            float alpha = __expf(m_r - mn);
            m_r = mn;

            // P = mask ? exp(leaky(S) - m) : 0 ; pack into PV B-fragments
            half8 pb[2];
            float sum = 0.f;
#pragma unroll
            for (int c = 0; c < 2; c++)
#pragma unroll
                for (int ntj = 0; ntj < 2; ntj++)
#pragma unroll
                    for (int r = 0; r < 4; r++) {
                        float e = S[c][ntj][r];
                        e = e > 0.f ? e : 0.2f * e;
                        bool bit = (mh[r] >> (c * 8 + quad * 2 + ntj)) & 1u;
                        float p = bit ? __expf(e - m_r) : 0.f;
                        sum += p;
                        pb[c][ntj * 4 + r] = (_Float16)p;
                    }
            sum += __shfl_xor(sum, 16);
            sum += __shfl_xor(sum, 32);
            l_r = l_r * alpha + sum;
#pragma unroll
            for (int nt = 0; nt < 8; nt++)
#pragma unroll
                for (int r = 0; r < 4; r++)
                    O[nt][r] *= alpha;

            // O^T += V^T P^T
#pragma unroll
            for (int c = 0; c < 2; c++)
#pragma unroll
                for (int nt = 0; nt < 8; nt++) {
                    half8 vf = *(const half8*)&KV[8192 + ((nt * 2 + c) * 64 + lane) * 8];
                    O[nt] = __builtin_amdgcn_mfma_f32_16x16x32_f16(vf, pb[c], O[nt], 0, 0, 0);
                }

            __syncthreads();   // b2: all waves done reading; next tile may land
        }
    }

    // epilogue: O^T[f][i] -> OpartT[js][f][i] (unnormalized) + (m,l)
#pragma unroll
    for (int nt = 0; nt < 8; nt++)
#pragma unroll
        for (int r = 0; r < 4; r++) {
            int f = nt * 16 + quad * 4 + r;
            OpartT[((size_t)js * FOUT + f) * N + iw + lo16] = O[nt][r];
        }
    if (quad == 0) {
        mpart[js * N + iw + lo16] = m_r;
        lpart[js * N + iw + lo16] = l_r;
    }
}

// ---------------------------------------------------------------------------
// Combine: f-major partials -> normalize -> ELU -> out[i][f].
// ---------------------------------------------------------------------------
template<int JS>
__global__ __launch_bounds__(256)
void combine_kernel(const float* __restrict__ OpartT,
                    const float* __restrict__ mpart,
                    const float* __restrict__ lpart,
                    float* __restrict__ out)
{
    int idx = blockIdx.x * 256 + threadIdx.x;   // 128 f x 2048 i-groups
    int f  = idx >> 11;
    int i4 = (idx & 2047) << 2;

    float4 M = {-3e38f, -3e38f, -3e38f, -3e38f};
    float4 m[JS];
#pragma unroll
    for (int s = 0; s < JS; s++) {
        m[s] = *(const float4*)&mpart[s * N + i4];
        M.x = fmaxf(M.x, m[s].x); M.y = fmaxf(M.y, m[s].y);
        M.z = fmaxf(M.z, m[s].z); M.w = fmaxf(M.w, m[s].w);
    }
    float4 L = {0.f, 0.f, 0.f, 0.f};
    float4 w[JS];
#pragma unroll
    for (int s = 0; s < JS; s++) {
        float4 l = *(const float4*)&lpart[s * N + i4];
        w[s].x = __expf(m[s].x - M.x); w[s].y = __expf(m[s].y - M.y);
        w[s].z = __expf(m[s].z - M.z); w[s].w = __expf(m[s].w - M.w);
        L.x += l.x * w[s].x; L.y += l.y * w[s].y;
        L.z += l.z * w[s].z; L.w += l.w * w[s].w;
    }
    float4 o = {0.f, 0.f, 0.f, 0.f};
#pragma unroll
    for (int s = 0; s < JS; s++) {
        float4 v = *(const float4*)&OpartT[((size_t)s * FOUT + f) * N + i4];
        o.x += w[s].x * v.x; o.y += w[s].y * v.y;
        o.z += w[s].z * v.z; o.w += w[s].w * v.w;
    }
    float r0 = o.x / L.x, r1 = o.y / L.y, r2 = o.z / L.z, r3 = o.w / L.w;
    out[(size_t)(i4 + 0) * FOUT + f] = r0 > 0.f ? r0 : __expf(r0) - 1.f;
    out[(size_t)(i4 + 1) * FOUT + f] = r1 > 0.f ? r1 : __expf(r1) - 1.f;
    out[(size_t)(i4 + 2) * FOUT + f] = r2 > 0.f ? r2 : __expf(r2) - 1.f;
    out[(size_t)(i4 + 3) * FOUT + f] = r3 > 0.f ? r3 : __expf(r3) - 1.f;
}

// ---------------------------------------------------------------------------
extern "C" void kernel_launch(void* const* d_in, const int* in_sizes, int n_in,
                              void* d_out, int out_size, void* d_ws, size_t ws_size,
                              hipStream_t stream) {
    const float* inp = (const float*)d_in[0];
    const int*   adj = (const int*)d_in[1];
    const float* W0  = (const float*)d_in[2];
    const float* W1  = (const float*)d_in[3];
    const float* W2  = (const float*)d_in[4];
    float* out = (float*)d_out;

    constexpr int JS = 8;
    char* ws = (char*)d_ws;
    _Float16* H    = (_Float16*)(ws);                          // 2 MB
    _Float16* H2   = (_Float16*)(ws + (2u << 20));             // 2 MB
    _Float16* H3T  = (_Float16*)(ws + (4u << 20));             // 2 MB
    _Float16* Wf   = (_Float16*)(ws + (6u << 20));             // 192 KB
    _Float16* Kf   = (_Float16*)(ws + (7u << 20));             // 2 MB
    _Float16* Vf   = (_Float16*)(ws + (9u << 20));             // 2 MB
    float* OpartT  = (float*)(ws + (11u << 20));               // 32 MB
    float* mpart   = (float*)(ws + (43u << 20));               // 256 KB
    float* lpart   = (float*)(ws + (43u << 20) + (size_t)JS * N * sizeof(float));

    wprep_kernel<<<48, 256, 0, stream>>>(W0, W1, W2, Wf);
    gemm3_kernel<<<dim3(N / 64, 2, 3), 256, 0, stream>>>(inp, Wf, H, H2, H3T);
    repackK_kernel<<<512, 256, 0, stream>>>(H2, Kf);
    repackV_kernel<<<512, 256, 0, stream>>>(H3T, Vf);
    attn_kernel<JS><<<(N / 64) * JS, 256, 0, stream>>>(H, Kf, Vf, adj, OpartT, mpart, lpart);
    combine_kernel<JS><<<(FOUT * (N / 4)) / 256, 256, 0, stream>>>(OpartT, mpart, lpart, out);
}

// Round 11
// 448.903 us; speedup vs baseline: 1.0317x; 1.0317x over previous
//
#include <hip/hip_runtime.h>
#include <hip/hip_fp16.h>

#define N    8192
#define FIN  256
#define FOUT 128
#define BN   64

typedef _Float16 half8 __attribute__((ext_vector_type(8)));
typedef _Float16 half4v __attribute__((ext_vector_type(4)));
typedef float floatx4 __attribute__((ext_vector_type(4)));

// ---------------------------------------------------------------------------
// W-prep: frag-major fp16 W for coalesced MFMA B-loads.
// ---------------------------------------------------------------------------
__global__ __launch_bounds__(256)
void wprep_kernel(const float* __restrict__ W0,
                  const float* __restrict__ W1,
                  const float* __restrict__ W2,
                  _Float16* __restrict__ Wf)
{
    int idx  = blockIdx.x * 256 + threadIdx.x;   // 0..12287
    int lane = idx & 63;
    int frag = idx >> 6;
    int w    = frag >> 6;
    int f    = frag & 63;
    int nt   = f >> 3, kc = f & 7;
    int quad = lane >> 4, lo16 = lane & 15;
    const float* Wp = w == 0 ? W0 : (w == 1 ? W1 : W2);
    half8 v;
#pragma unroll
    for (int jj = 0; jj < 8; jj++)
        v[jj] = (_Float16)Wp[(size_t)(kc * 32 + quad * 8 + jj) * FOUT + nt * 16 + lo16];
    *(half8*)&Wf[(size_t)idx * 8] = v;
}

// ---------------------------------------------------------------------------
// H = fp16(inp@W), H2 = fp16(inp@W2), H3T = fp16((inp@W3)^T). Barrier-free.
// ---------------------------------------------------------------------------
__global__ __launch_bounds__(256, 2)
void gemm3_kernel(const float* __restrict__ inp,
                  const _Float16* __restrict__ Wf,
                  _Float16* __restrict__ H,
                  _Float16* __restrict__ H2,
                  _Float16* __restrict__ H3T)
{
    const int which = blockIdx.z;
    const int c0    = blockIdx.y * 64;
    const _Float16* Wfw = Wf + (size_t)which * 64 * 64 * 8;
    const int r0 = blockIdx.x * 64;
    const int tid  = threadIdx.x;
    const int wave = tid >> 6;
    const int lane = tid & 63;
    const int lo16 = lane & 15;
    const int quad = lane >> 4;
    const int r = r0 + wave * 16 + lo16;

    half8 a[8];
#pragma unroll
    for (int kc = 0; kc < 8; kc++) {
        const float* p = &inp[(size_t)r * FIN + kc * 32 + quad * 8];
        float4 v0 = *(const float4*)p;
        float4 v1 = *(const float4*)(p + 4);
        a[kc][0] = (_Float16)v0.x; a[kc][1] = (_Float16)v0.y;
        a[kc][2] = (_Float16)v0.z; a[kc][3] = (_Float16)v0.w;
        a[kc][4] = (_Float16)v1.x; a[kc][5] = (_Float16)v1.y;
        a[kc][6] = (_Float16)v1.z; a[kc][7] = (_Float16)v1.w;
    }

    floatx4 acc[4];
#pragma unroll
    for (int i = 0; i < 4; i++) acc[i] = (floatx4){0.f, 0.f, 0.f, 0.f};

#pragma unroll
    for (int kc = 0; kc < 8; kc++)
#pragma unroll
        for (int nt = 0; nt < 4; nt++) {
            int ntg = (c0 >> 4) + nt;
            half8 b = *(const half8*)&Wfw[(((size_t)ntg * 8 + kc) * 64 + lane) * 8];
            acc[nt] = __builtin_amdgcn_mfma_f32_16x16x32_f16(a[kc], b, acc[nt], 0, 0, 0);
        }

    const int arow = wave * 16 + quad * 4;
    if (which < 2) {
        _Float16* outp = which == 0 ? H : H2;
#pragma unroll
        for (int nt = 0; nt < 4; nt++)
#pragma unroll
            for (int rr = 0; rr < 4; rr++)
                outp[(size_t)(r0 + arow + rr) * FOUT + c0 + nt * 16 + lo16] = (_Float16)acc[nt][rr];
    } else {
#pragma unroll
        for (int nt = 0; nt < 4; nt++) {
            half4v v;
#pragma unroll
            for (int rr = 0; rr < 4; rr++) v[rr] = (_Float16)acc[nt][rr];
            *(half4v*)&H3T[(size_t)(c0 + nt * 16 + lo16) * N + r0 + arow] = v;
        }
    }
}

// ---------------------------------------------------------------------------
// Fused repack: blocks [0,512) build Kf (sigma j-permutation baked in),
// blocks [512,1024) build Vf. One launch instead of two.
// ---------------------------------------------------------------------------
__global__ __launch_bounds__(256)
void repackKV_kernel(const _Float16* __restrict__ H2,
                     const _Float16* __restrict__ H3T,
                     _Float16* __restrict__ Kf,
                     _Float16* __restrict__ Vf)
{
    if (blockIdx.x < 512) {
        int idx  = blockIdx.x * 256 + threadIdx.x;
        int lane = idx & 63;
        int frag = idx >> 6;
        int jb = frag >> 4, f = frag & 15;
        int c = f >> 3, ntj = (f >> 2) & 1, kc = f & 3;
        int quad = lane >> 4, lo16 = lane & 15;
        int srcrow = jb * 64 + c * 32 + (lo16 >> 2) * 8 + ntj * 4 + (lo16 & 3);
        half8 v = *(const half8*)&H2[(size_t)srcrow * FOUT + kc * 32 + quad * 8];
        *(half8*)&Kf[(size_t)idx * 8] = v;
    } else {
        int idx  = (blockIdx.x - 512) * 256 + threadIdx.x;
        int lane = idx & 63;
        int frag = idx >> 6;
        int jb = frag >> 4, f = frag & 15, nt = f >> 1, kc = f & 1;
        int quad = lane >> 4, lo16 = lane & 15;
        half8 v = *(const half8*)&H3T[(size_t)(nt * 16 + lo16) * N + jb * 64 + kc * 32 + quad * 8];
        *(half8*)&Vf[(size_t)idx * 8] = v;
    }
}

// ---------------------------------------------------------------------------
// Flash attention v7: S^T formulation, 32 i-rows/wave, dbuf KV LDS,
// 1 barrier/iter. Adjacency folded in (ballot at top consumes loads issued
// last iteration). NEW: each 64-j window processed as TWO 32-j online-softmax
// half-passes -> shorter QK->softmax->PV dependency chain, halved S/pb regs,
// PV MFMAs of half c overlap softmax VALU of half c+1.
// ---------------------------------------------------------------------------
template<int JS>
__global__ __launch_bounds__(256, 2)
void attn_kernel(const _Float16* __restrict__ Hq,   // [N][128]
                 const _Float16* __restrict__ Kf,   // permuted frag-major
                 const _Float16* __restrict__ Vf,   // frag-major
                 const int* __restrict__ adj,       // [N][N]
                 float* __restrict__ OpartT,        // [JS][FOUT][N]
                 float* __restrict__ mpart,         // [JS][N]
                 float* __restrict__ lpart)         // [JS][N]
{
    __shared__ _Float16 KV[2][16384];   // [buf][16 K frags | 16 V frags]

    const int tid  = threadIdx.x;
    const int wave = tid >> 6;
    const int lane = tid & 63;
    const int lo16 = lane & 15;
    const int quad = lane >> 4;
    const int bid  = blockIdx.x;
    const int js   = bid & (JS - 1);      // XCD affinity
    const int ib   = bid / JS;
    const int i0   = ib * 128;
    const int iw   = i0 + wave * 32;
    const int jbeg = js * (N / JS);
    const int NIT  = (N / JS) / BN;

    // Q as B-operand fragments for 2 i-subtiles
    half8 q[2][4];
#pragma unroll
    for (int isub = 0; isub < 2; isub++)
#pragma unroll
        for (int kc = 0; kc < 4; kc++)
            q[isub][kc] = *(const half8*)&Hq[(size_t)(iw + isub * 16 + lo16) * FOUT + kc * 32 + quad * 8];

    floatx4 O[8][2];
#pragma unroll
    for (int nt = 0; nt < 8; nt++)
#pragma unroll
        for (int s = 0; s < 2; s++) O[nt][s] = (floatx4){0.f, 0.f, 0.f, 0.f};
    float m_s[2] = {-1e12f, -1e12f}, l_s[2] = {0.f, 0.f};

    // prologue: adj window 0 loads
    int av[32];
    {
        const int* ap = adj + (size_t)iw * N + jbeg + lane;
#pragma unroll
        for (int x = 0; x < 32; x++) av[x] = ap[(size_t)x * N];
    }

    // prologue: stage KV tile 0 into buf 0
    {
        const int jb0 = jbeg >> 6;
        const _Float16* gk = Kf + (size_t)jb0 * 8192;
        const _Float16* gv = Vf + (size_t)jb0 * 8192;
#pragma unroll
        for (int r = 0; r < 4; r++) {
            int off = (r * 256 + tid) * 8;
            *(half8*)&KV[0][off]        = *(const half8*)&gk[off];
            *(half8*)&KV[0][8192 + off] = *(const half8*)&gv[off];
        }
        __syncthreads();
    }

    int cur = 0;
    for (int it = 0; it < NIT; it++) {
        const int j0 = jbeg + it * BN;

        // ---- 1) ballot the adj window loaded one iteration ago ----
        unsigned long long mw0 = 0, mw1 = 0;
#pragma unroll
        for (int x = 0; x < 16; x++) {
            unsigned long long b0 = __ballot(av[x] != 0);
            unsigned long long b1 = __ballot(av[x + 16] != 0);
            bool sel = (lo16 == x);
            mw0 = sel ? b0 : mw0;
            mw1 = sel ? b1 : mw1;
        }
        unsigned long long mw[2] = {mw0, mw1};

        // ---- 2) prefetch next KV tile into regs (issued BEFORE adj so the
        //         ds_write wait is vmcnt(32), not vmcnt(0)) ----
        half8 st[8];
        if (it + 1 < NIT) {
            const int jbn = (j0 + BN) >> 6;
            const _Float16* gk = Kf + (size_t)jbn * 8192;
            const _Float16* gv = Vf + (size_t)jbn * 8192;
#pragma unroll
            for (int r = 0; r < 4; r++) {
                int off = (r * 256 + tid) * 8;
                st[r]     = *(const half8*)&gk[off];
                st[r + 4] = *(const half8*)&gv[off];
            }
        }

        // ---- 3) issue adj loads for the NEXT window ----
        if (it + 1 < NIT) {
            const int* ap = adj + (size_t)iw * N + (j0 + BN) + lane;
#pragma unroll
            for (int x = 0; x < 32; x++) av[x] = ap[(size_t)x * N];
        }

        const _Float16* kb = &KV[cur][0];
        const _Float16* vb = &KV[cur][8192];

        // ---- 4) two 32-j online-softmax half-passes ----
#pragma unroll
        for (int c = 0; c < 2; c++) {
            // S^T half: j = c*32 + 8*quad + 4*ntj + r, i = isub*16 + lo16
            floatx4 S[2][2];   // [ntj][isub]
#pragma unroll
            for (int ntj = 0; ntj < 2; ntj++) {
                S[ntj][0] = (floatx4){0.f, 0.f, 0.f, 0.f};
                S[ntj][1] = (floatx4){0.f, 0.f, 0.f, 0.f};
#pragma unroll
                for (int kc = 0; kc < 4; kc++) {
                    half8 kf = *(const half8*)&kb[(((c * 2 + ntj) * 4 + kc) * 64 + lane) * 8];
                    S[ntj][0] = __builtin_amdgcn_mfma_f32_16x16x32_f16(kf, q[0][kc], S[ntj][0], 0, 0, 0);
                    S[ntj][1] = __builtin_amdgcn_mfma_f32_16x16x32_f16(kf, q[1][kc], S[ntj][1], 0, 0, 0);
                }
            }

            // per-i running max over this half (LeakyReLU inline)
            float alpha[2];
#pragma unroll
            for (int s = 0; s < 2; s++) {
                float mx = -1e12f;
#pragma unroll
                for (int ntj = 0; ntj < 2; ntj++)
#pragma unroll
                    for (int r = 0; r < 4; r++) {
                        float e = S[ntj][s][r];
                        e = e > 0.f ? e : 0.2f * e;
                        mx = fmaxf(mx, e);
                    }
                mx = fmaxf(mx, __shfl_xor(mx, 16));
                mx = fmaxf(mx, __shfl_xor(mx, 32));
                float mn = fmaxf(m_s[s], mx);
                alpha[s] = __expf(m_s[s] - mn);
                m_s[s] = mn;
            }

            // P = mask ? exp(leaky(S) - m) : 0 ; pack into PV B-fragment
            half8 pb[2];
            float sum[2] = {0.f, 0.f};
#pragma unroll
            for (int s = 0; s < 2; s++) {
                unsigned long long mq = mw[s] >> (quad * 8 + c * 32);
#pragma unroll
                for (int ntj = 0; ntj < 2; ntj++)
#pragma unroll
                    for (int r = 0; r < 4; r++) {
                        float e = S[ntj][s][r];
                        e = e > 0.f ? e : 0.2f * e;
                        bool bit = (mq >> (ntj * 4 + r)) & 1ull;
                        float p = bit ? __expf(e - m_s[s]) : 0.f;
                        sum[s] += p;
                        pb[s][ntj * 4 + r] = (_Float16)p;
                    }
                sum[s] += __shfl_xor(sum[s], 16);
                sum[s] += __shfl_xor(sum[s], 32);
                l_s[s] = l_s[s] * alpha[s] + sum[s];
#pragma unroll
                for (int nt = 0; nt < 8; nt++)
#pragma unroll
                    for (int r = 0; r < 4; r++)
                        O[nt][s][r] *= alpha[s];
            }

            // O^T += V^T P^T for this half
#pragma unroll
            for (int nt = 0; nt < 8; nt++) {
                half8 vf = *(const half8*)&vb[((nt * 2 + c) * 64 + lane) * 8];
                O[nt][0] = __builtin_amdgcn_mfma_f32_16x16x32_f16(vf, pb[0], O[nt][0], 0, 0, 0);
                O[nt][1] = __builtin_amdgcn_mfma_f32_16x16x32_f16(vf, pb[1], O[nt][1], 0, 0, 0);
            }
        }

        // ---- 5) commit prefetched KV tile; one barrier per iter ----
        if (it + 1 < NIT) {
            const int nxt = cur ^ 1;
#pragma unroll
            for (int r = 0; r < 4; r++) {
                int off = (r * 256 + tid) * 8;
                *(half8*)&KV[nxt][off]        = st[r];
                *(half8*)&KV[nxt][8192 + off] = st[r + 4];
            }
        }
        __syncthreads();
        cur ^= 1;
    }

    // epilogue: O^T[f][i] -> OpartT[js][f][i] (unnormalized) + (m,l)
#pragma unroll
    for (int nt = 0; nt < 8; nt++)
#pragma unroll
        for (int s = 0; s < 2; s++)
#pragma unroll
            for (int r = 0; r < 4; r++) {
                int f = nt * 16 + quad * 4 + r;
                int i = iw + s * 16 + lo16;
                OpartT[((size_t)js * FOUT + f) * N + i] = O[nt][s][r];
            }
    if (quad == 0) {
#pragma unroll
        for (int s = 0; s < 2; s++) {
            mpart[js * N + iw + s * 16 + lo16] = m_s[s];
            lpart[js * N + iw + s * 16 + lo16] = l_s[s];
        }
    }
}

// ---------------------------------------------------------------------------
// Combine: f-major partials -> normalize -> ELU -> out[i][f].
// ---------------------------------------------------------------------------
template<int JS>
__global__ __launch_bounds__(256)
void combine_kernel(const float* __restrict__ OpartT,
                    const float* __restrict__ mpart,
                    const float* __restrict__ lpart,
                    float* __restrict__ out)
{
    int idx = blockIdx.x * 256 + threadIdx.x;   // 128 f x 2048 i-groups
    int f  = idx >> 11;
    int i4 = (idx & 2047) << 2;

    float4 M = {-3e38f, -3e38f, -3e38f, -3e38f};
    float4 m[JS];
#pragma unroll
    for (int s = 0; s < JS; s++) {
        m[s] = *(const float4*)&mpart[s * N + i4];
        M.x = fmaxf(M.x, m[s].x); M.y = fmaxf(M.y, m[s].y);
        M.z = fmaxf(M.z, m[s].z); M.w = fmaxf(M.w, m[s].w);
    }
    float4 L = {0.f, 0.f, 0.f, 0.f};
    float4 w[JS];
#pragma unroll
    for (int s = 0; s < JS; s++) {
        float4 l = *(const float4*)&lpart[s * N + i4];
        w[s].x = __expf(m[s].x - M.x); w[s].y = __expf(m[s].y - M.y);
        w[s].z = __expf(m[s].z - M.z); w[s].w = __expf(m[s].w - M.w);
        L.x += l.x * w[s].x; L.y += l.y * w[s].y;
        L.z += l.z * w[s].z; L.w += l.w * w[s].w;
    }
    float4 o = {0.f, 0.f, 0.f, 0.f};
#pragma unroll
    for (int s = 0; s < JS; s++) {
        float4 v = *(const float4*)&OpartT[((size_t)s * FOUT + f) * N + i4];
        o.x += w[s].x * v.x; o.y += w[s].y * v.y;
        o.z += w[s].z * v.z; o.w += w[s].w * v.w;
    }
    float r0 = o.x / L.x, r1 = o.y / L.y, r2 = o.z / L.z, r3 = o.w / L.w;
    out[(size_t)(i4 + 0) * FOUT + f] = r0 > 0.f ? r0 : __expf(r0) - 1.f;
    out[(size_t)(i4 + 1) * FOUT + f] = r1 > 0.f ? r1 : __expf(r1) - 1.f;
    out[(size_t)(i4 + 2) * FOUT + f] = r2 > 0.f ? r2 : __expf(r2) - 1.f;
    out[(size_t)(i4 + 3) * FOUT + f] = r3 > 0.f ? r3 : __expf(r3) - 1.f;
}

// ---------------------------------------------------------------------------
extern "C" void kernel_launch(void* const* d_in, const int* in_sizes, int n_in,
                              void* d_out, int out_size, void* d_ws, size_t ws_size,
                              hipStream_t stream) {
    const float* inp = (const float*)d_in[0];
    const int*   adj = (const int*)d_in[1];
    const float* W0  = (const float*)d_in[2];
    const float* W1  = (const float*)d_in[3];
    const float* W2  = (const float*)d_in[4];
    float* out = (float*)d_out;

    constexpr int JS = 8;
    char* ws = (char*)d_ws;
    _Float16* H    = (_Float16*)(ws);                          // 2 MB
    _Float16* H2   = (_Float16*)(ws + (2u << 20));             // 2 MB
    _Float16* H3T  = (_Float16*)(ws + (4u << 20));             // 2 MB
    _Float16* Wf   = (_Float16*)(ws + (6u << 20));             // 192 KB
    _Float16* Kf   = (_Float16*)(ws + (7u << 20));             // 2 MB
    _Float16* Vf   = (_Float16*)(ws + (9u << 20));             // 2 MB
    float* OpartT  = (float*)(ws + (11u << 20));               // 32 MB
    float* mpart   = (float*)(ws + (43u << 20));               // 256 KB
    float* lpart   = (float*)(ws + (43u << 20) + (size_t)JS * N * sizeof(float));

    wprep_kernel<<<48, 256, 0, stream>>>(W0, W1, W2, Wf);
    gemm3_kernel<<<dim3(N / 64, 2, 3), 256, 0, stream>>>(inp, Wf, H, H2, H3T);
    repackKV_kernel<<<1024, 256, 0, stream>>>(H2, H3T, Kf, Vf);
    attn_kernel<JS><<<(N / 128) * JS, 256, 0, stream>>>(H, Kf, Vf, adj, OpartT, mpart, lpart);
    combine_kernel<JS><<<(FOUT * (N / 4)) / 256, 256, 0, stream>>>(OpartT, mpart, lpart, out);
}

// Round 12
// 448.276 us; speedup vs baseline: 1.0331x; 1.0014x over previous
//
#include <hip/hip_runtime.h>
#include <hip/hip_fp16.h>

#define N    8192
#define FIN  256
#define FOUT 128
#define BN   64

typedef _Float16 half8 __attribute__((ext_vector_type(8)));
typedef _Float16 half4v __attribute__((ext_vector_type(4)));
typedef float floatx4 __attribute__((ext_vector_type(4)));

// ---------------------------------------------------------------------------
// W-prep: frag-major fp16 W for coalesced MFMA B-loads.
// ---------------------------------------------------------------------------
__global__ __launch_bounds__(256)
void wprep_kernel(const float* __restrict__ W0,
                  const float* __restrict__ W1,
                  const float* __restrict__ W2,
                  _Float16* __restrict__ Wf)
{
    int idx  = blockIdx.x * 256 + threadIdx.x;   // 0..12287
    int lane = idx & 63;
    int frag = idx >> 6;
    int w    = frag >> 6;
    int f    = frag & 63;
    int nt   = f >> 3, kc = f & 7;
    int quad = lane >> 4, lo16 = lane & 15;
    const float* Wp = w == 0 ? W0 : (w == 1 ? W1 : W2);
    half8 v;
#pragma unroll
    for (int jj = 0; jj < 8; jj++)
        v[jj] = (_Float16)Wp[(size_t)(kc * 32 + quad * 8 + jj) * FOUT + nt * 16 + lo16];
    *(half8*)&Wf[(size_t)idx * 8] = v;
}

// ---------------------------------------------------------------------------
// H = fp16(inp@W), H2 = fp16(inp@W2), H3T = fp16((inp@W3)^T). Barrier-free.
// ---------------------------------------------------------------------------
__global__ __launch_bounds__(256, 2)
void gemm3_kernel(const float* __restrict__ inp,
                  const _Float16* __restrict__ Wf,
                  _Float16* __restrict__ H,
                  _Float16* __restrict__ H2,
                  _Float16* __restrict__ H3T)
{
    const int which = blockIdx.z;
    const int c0    = blockIdx.y * 64;
    const _Float16* Wfw = Wf + (size_t)which * 64 * 64 * 8;
    const int r0 = blockIdx.x * 64;
    const int tid  = threadIdx.x;
    const int wave = tid >> 6;
    const int lane = tid & 63;
    const int lo16 = lane & 15;
    const int quad = lane >> 4;
    const int r = r0 + wave * 16 + lo16;

    half8 a[8];
#pragma unroll
    for (int kc = 0; kc < 8; kc++) {
        const float* p = &inp[(size_t)r * FIN + kc * 32 + quad * 8];
        float4 v0 = *(const float4*)p;
        float4 v1 = *(const float4*)(p + 4);
        a[kc][0] = (_Float16)v0.x; a[kc][1] = (_Float16)v0.y;
        a[kc][2] = (_Float16)v0.z; a[kc][3] = (_Float16)v0.w;
        a[kc][4] = (_Float16)v1.x; a[kc][5] = (_Float16)v1.y;
        a[kc][6] = (_Float16)v1.z; a[kc][7] = (_Float16)v1.w;
    }

    floatx4 acc[4];
#pragma unroll
    for (int i = 0; i < 4; i++) acc[i] = (floatx4){0.f, 0.f, 0.f, 0.f};

#pragma unroll
    for (int kc = 0; kc < 8; kc++)
#pragma unroll
        for (int nt = 0; nt < 4; nt++) {
            int ntg = (c0 >> 4) + nt;
            half8 b = *(const half8*)&Wfw[(((size_t)ntg * 8 + kc) * 64 + lane) * 8];
            acc[nt] = __builtin_amdgcn_mfma_f32_16x16x32_f16(a[kc], b, acc[nt], 0, 0, 0);
        }

    const int arow = wave * 16 + quad * 4;
    if (which < 2) {
        _Float16* outp = which == 0 ? H : H2;
#pragma unroll
        for (int nt = 0; nt < 4; nt++)
#pragma unroll
            for (int rr = 0; rr < 4; rr++)
                outp[(size_t)(r0 + arow + rr) * FOUT + c0 + nt * 16 + lo16] = (_Float16)acc[nt][rr];
    } else {
#pragma unroll
        for (int nt = 0; nt < 4; nt++) {
            half4v v;
#pragma unroll
            for (int rr = 0; rr < 4; rr++) v[rr] = (_Float16)acc[nt][rr];
            *(half4v*)&H3T[(size_t)(c0 + nt * 16 + lo16) * N + r0 + arow] = v;
        }
    }
}

// ---------------------------------------------------------------------------
// Fused repack: blocks [0,512) build Kf (sigma j-permutation baked in),
// blocks [512,1024) build Vf.
// ---------------------------------------------------------------------------
__global__ __launch_bounds__(256)
void repackKV_kernel(const _Float16* __restrict__ H2,
                     const _Float16* __restrict__ H3T,
                     _Float16* __restrict__ Kf,
                     _Float16* __restrict__ Vf)
{
    if (blockIdx.x < 512) {
        int idx  = blockIdx.x * 256 + threadIdx.x;
        int lane = idx & 63;
        int frag = idx >> 6;
        int jb = frag >> 4, f = frag & 15;
        int c = f >> 3, ntj = (f >> 2) & 1, kc = f & 3;
        int quad = lane >> 4, lo16 = lane & 15;
        int srcrow = jb * 64 + c * 32 + (lo16 >> 2) * 8 + ntj * 4 + (lo16 & 3);
        half8 v = *(const half8*)&H2[(size_t)srcrow * FOUT + kc * 32 + quad * 8];
        *(half8*)&Kf[(size_t)idx * 8] = v;
    } else {
        int idx  = (blockIdx.x - 512) * 256 + threadIdx.x;
        int lane = idx & 63;
        int frag = idx >> 6;
        int jb = frag >> 4, f = frag & 15, nt = f >> 1, kc = f & 1;
        int quad = lane >> 4, lo16 = lane & 15;
        half8 v = *(const half8*)&H3T[(size_t)(nt * 16 + lo16) * N + jb * 64 + kc * 32 + quad * 8];
        *(half8*)&Vf[(size_t)idx * 8] = v;
    }
}

// ---------------------------------------------------------------------------
// Flash attention v8: FULLY BARRIER-FREE. No LDS, no __syncthreads.
// 32 i-rows/wave; K frags (16 x 1KB coalesced, L2-hot) loaded per window
// BEFORE issuing next-window adj loads (FIFO: QK waits vmcnt(32), adj stays
// in flight a full iteration). V frags inline in the PV loop. Single-pass
// online softmax over the 64-j window (R9 math).
// ---------------------------------------------------------------------------
template<int JS>
__global__ __launch_bounds__(256, 2)
void attn_kernel(const _Float16* __restrict__ Hq,   // [N][128]
                 const _Float16* __restrict__ Kf,   // permuted frag-major
                 const _Float16* __restrict__ Vf,   // frag-major
                 const int* __restrict__ adj,       // [N][N]
                 float* __restrict__ OpartT,        // [JS][FOUT][N]
                 float* __restrict__ mpart,         // [JS][N]
                 float* __restrict__ lpart)         // [JS][N]
{
    const int tid  = threadIdx.x;
    const int wave = tid >> 6;
    const int lane = tid & 63;
    const int lo16 = lane & 15;
    const int quad = lane >> 4;
    const int bid  = blockIdx.x;
    const int js   = bid & (JS - 1);      // XCD affinity
    const int ib   = bid / JS;
    const int iw   = ib * 128 + wave * 32;
    const int jbeg = js * (N / JS);
    const int NIT  = (N / JS) / BN;

    // Q as B-operand fragments for 2 i-subtiles (loop-invariant)
    half8 q[2][4];
#pragma unroll
    for (int isub = 0; isub < 2; isub++)
#pragma unroll
        for (int kc = 0; kc < 4; kc++)
            q[isub][kc] = *(const half8*)&Hq[(size_t)(iw + isub * 16 + lo16) * FOUT + kc * 32 + quad * 8];

    floatx4 O[8][2];
#pragma unroll
    for (int nt = 0; nt < 8; nt++)
#pragma unroll
        for (int s = 0; s < 2; s++) O[nt][s] = (floatx4){0.f, 0.f, 0.f, 0.f};
    float m_s[2] = {-1e12f, -1e12f}, l_s[2] = {0.f, 0.f};

    // prologue: issue adj window 0 (full iteration of slack before ballot)
    int av[32];
    {
        const int* ap = adj + (size_t)iw * N + jbeg + lane;
#pragma unroll
        for (int x = 0; x < 32; x++) av[x] = ap[(size_t)x * N];
    }

    for (int it = 0; it < NIT; it++) {
        const int j0 = jbeg + it * BN;
        const int jb = j0 >> 6;
        const _Float16* gk = Kf + (size_t)jb * 8192;
        const _Float16* gv = Vf + (size_t)jb * 8192;

        // ---- 1) ballot the adj window prefetched last iteration ----
        unsigned long long mw0 = 0, mw1 = 0;
#pragma unroll
        for (int x = 0; x < 16; x++) {
            unsigned long long b0 = __ballot(av[x] != 0);
            unsigned long long b1 = __ballot(av[x + 16] != 0);
            bool sel = (lo16 == x);
            mw0 = sel ? b0 : mw0;
            mw1 = sel ? b1 : mw1;
        }
        unsigned long long mw[2] = {mw0, mw1};

        // ---- 2) issue ALL 16 K-frag loads (1KB coalesced each, L2-hot) ----
        half8 kf[16];
#pragma unroll
        for (int f = 0; f < 16; f++)
            kf[f] = *(const half8*)&gk[((size_t)f * 64 + lane) * 8];

        // ---- 3) THEN issue next-window adj loads (stay in flight: QK's
        //         wait is vmcnt(32), not vmcnt(0)) ----
        if (it + 1 < NIT) {
            const int* ap = adj + (size_t)iw * N + (j0 + BN) + lane;
#pragma unroll
            for (int x = 0; x < 32; x++) av[x] = ap[(size_t)x * N];
        }

        // ---- 4) S^T = K Q^T : j = c*32 + 8*quad + 4*ntj + r, i = s*16+lo16
        floatx4 S[2][2][2];   // [c][ntj][isub]
#pragma unroll
        for (int c = 0; c < 2; c++)
#pragma unroll
            for (int ntj = 0; ntj < 2; ntj++) {
                S[c][ntj][0] = (floatx4){0.f, 0.f, 0.f, 0.f};
                S[c][ntj][1] = (floatx4){0.f, 0.f, 0.f, 0.f};
#pragma unroll
                for (int kc = 0; kc < 4; kc++) {
                    half8 k8 = kf[(c * 2 + ntj) * 4 + kc];
                    S[c][ntj][0] = __builtin_amdgcn_mfma_f32_16x16x32_f16(k8, q[0][kc], S[c][ntj][0], 0, 0, 0);
                    S[c][ntj][1] = __builtin_amdgcn_mfma_f32_16x16x32_f16(k8, q[1][kc], S[c][ntj][1], 0, 0, 0);
                }
            }

        // ---- 5) single-pass online softmax over the 64-j window ----
        float alpha[2];
#pragma unroll
        for (int s = 0; s < 2; s++) {
            float mx = -1e12f;
#pragma unroll
            for (int c = 0; c < 2; c++)
#pragma unroll
                for (int ntj = 0; ntj < 2; ntj++)
#pragma unroll
                    for (int r = 0; r < 4; r++) {
                        float e = S[c][ntj][s][r];
                        e = e > 0.f ? e : 0.2f * e;
                        mx = fmaxf(mx, e);
                    }
            mx = fmaxf(mx, __shfl_xor(mx, 16));
            mx = fmaxf(mx, __shfl_xor(mx, 32));
            float mn = fmaxf(m_s[s], mx);
            alpha[s] = __expf(m_s[s] - mn);
            m_s[s] = mn;
        }

        half8 pb[2][2];       // [isub][c], element jj = 4*ntj + r
        float sum[2] = {0.f, 0.f};
#pragma unroll
        for (int s = 0; s < 2; s++) {
            unsigned long long mq = mw[s] >> (quad * 8);
#pragma unroll
            for (int c = 0; c < 2; c++)
#pragma unroll
                for (int ntj = 0; ntj < 2; ntj++)
#pragma unroll
                    for (int r = 0; r < 4; r++) {
                        float e = S[c][ntj][s][r];
                        e = e > 0.f ? e : 0.2f * e;
                        bool bit = (mq >> (c * 32 + ntj * 4 + r)) & 1ull;
                        float p = bit ? __expf(e - m_s[s]) : 0.f;
                        sum[s] += p;
                        pb[s][c][ntj * 4 + r] = (_Float16)p;
                    }
            sum[s] += __shfl_xor(sum[s], 16);
            sum[s] += __shfl_xor(sum[s], 32);
            l_s[s] = l_s[s] * alpha[s] + sum[s];
#pragma unroll
            for (int nt = 0; nt < 8; nt++)
#pragma unroll
                for (int r = 0; r < 4; r++)
                    O[nt][s][r] *= alpha[s];
        }

        // ---- 6) O^T += V^T P^T, V frags inline (L2-hot, few in flight) ----
#pragma unroll
        for (int c = 0; c < 2; c++)
#pragma unroll
            for (int nt = 0; nt < 8; nt++) {
                half8 vf = *(const half8*)&gv[(((size_t)nt * 2 + c) * 64 + lane) * 8];
                O[nt][0] = __builtin_amdgcn_mfma_f32_16x16x32_f16(vf, pb[0][c], O[nt][0], 0, 0, 0);
                O[nt][1] = __builtin_amdgcn_mfma_f32_16x16x32_f16(vf, pb[1][c], O[nt][1], 0, 0, 0);
            }
    }

    // epilogue: O^T[f][i] -> OpartT[js][f][i] (unnormalized) + (m,l)
#pragma unroll
    for (int nt = 0; nt < 8; nt++)
#pragma unroll
        for (int s = 0; s < 2; s++)
#pragma unroll
            for (int r = 0; r < 4; r++) {
                int f = nt * 16 + quad * 4 + r;
                int i = iw + s * 16 + lo16;
                OpartT[((size_t)js * FOUT + f) * N + i] = O[nt][s][r];
            }
    if (quad == 0) {
#pragma unroll
        for (int s = 0; s < 2; s++) {
            mpart[js * N + iw + s * 16 + lo16] = m_s[s];
            lpart[js * N + iw + s * 16 + lo16] = l_s[s];
        }
    }
}

// ---------------------------------------------------------------------------
// Combine: f-major partials -> normalize -> ELU -> out[i][f].
// ---------------------------------------------------------------------------
template<int JS>
__global__ __launch_bounds__(256)
void combine_kernel(const float* __restrict__ OpartT,
                    const float* __restrict__ mpart,
                    const float* __restrict__ lpart,
                    float* __restrict__ out)
{
    int idx = blockIdx.x * 256 + threadIdx.x;   // 128 f x 2048 i-groups
    int f  = idx >> 11;
    int i4 = (idx & 2047) << 2;

    float4 M = {-3e38f, -3e38f, -3e38f, -3e38f};
    float4 m[JS];
#pragma unroll
    for (int s = 0; s < JS; s++) {
        m[s] = *(const float4*)&mpart[s * N + i4];
        M.x = fmaxf(M.x, m[s].x); M.y = fmaxf(M.y, m[s].y);
        M.z = fmaxf(M.z, m[s].z); M.w = fmaxf(M.w, m[s].w);
    }
    float4 L = {0.f, 0.f, 0.f, 0.f};
    float4 w[JS];
#pragma unroll
    for (int s = 0; s < JS; s++) {
        float4 l = *(const float4*)&lpart[s * N + i4];
        w[s].x = __expf(m[s].x - M.x); w[s].y = __expf(m[s].y - M.y);
        w[s].z = __expf(m[s].z - M.z); w[s].w = __expf(m[s].w - M.w);
        L.x += l.x * w[s].x; L.y += l.y * w[s].y;
        L.z += l.z * w[s].z; L.w += l.w * w[s].w;
    }
    float4 o = {0.f, 0.f, 0.f, 0.f};
#pragma unroll
    for (int s = 0; s < JS; s++) {
        float4 v = *(const float4*)&OpartT[((size_t)s * FOUT + f) * N + i4];
        o.x += w[s].x * v.x; o.y += w[s].y * v.y;
        o.z += w[s].z * v.z; o.w += w[s].w * v.w;
    }
    float r0 = o.x / L.x, r1 = o.y / L.y, r2 = o.z / L.z, r3 = o.w / L.w;
    out[(size_t)(i4 + 0) * FOUT + f] = r0 > 0.f ? r0 : __expf(r0) - 1.f;
    out[(size_t)(i4 + 1) * FOUT + f] = r1 > 0.f ? r1 : __expf(r1) - 1.f;
    out[(size_t)(i4 + 2) * FOUT + f] = r2 > 0.f ? r2 : __expf(r2) - 1.f;
    out[(size_t)(i4 + 3) * FOUT + f] = r3 > 0.f ? r3 : __expf(r3) - 1.f;
}

// ---------------------------------------------------------------------------
extern "C" void kernel_launch(void* const* d_in, const int* in_sizes, int n_in,
                              void* d_out, int out_size, void* d_ws, size_t ws_size,
                              hipStream_t stream) {
    const float* inp = (const float*)d_in[0];
    const int*   adj = (const int*)d_in[1];
    const float* W0  = (const float*)d_in[2];
    const float* W1  = (const float*)d_in[3];
    const float* W2  = (const float*)d_in[4];
    float* out = (float*)d_out;

    constexpr int JS = 8;
    char* ws = (char*)d_ws;
    _Float16* H    = (_Float16*)(ws);                          // 2 MB
    _Float16* H2   = (_Float16*)(ws + (2u << 20));             // 2 MB
    _Float16* H3T  = (_Float16*)(ws + (4u << 20));             // 2 MB
    _Float16* Wf   = (_Float16*)(ws + (6u << 20));             // 192 KB
    _Float16* Kf   = (_Float16*)(ws + (7u << 20));             // 2 MB
    _Float16* Vf   = (_Float16*)(ws + (9u << 20));             // 2 MB
    float* OpartT  = (float*)(ws + (11u << 20));               // 32 MB
    float* mpart   = (float*)(ws + (43u << 20));               // 256 KB
    float* lpart   = (float*)(ws + (43u << 20) + (size_t)JS * N * sizeof(float));

    wprep_kernel<<<48, 256, 0, stream>>>(W0, W1, W2, Wf);
    gemm3_kernel<<<dim3(N / 64, 2, 3), 256, 0, stream>>>(inp, Wf, H, H2, H3T);
    repackKV_kernel<<<1024, 256, 0, stream>>>(H2, H3T, Kf, Vf);
    attn_kernel<JS><<<(N / 128) * JS, 256, 0, stream>>>(H, Kf, Vf, adj, OpartT, mpart, lpart);
    combine_kernel<JS><<<(FOUT * (N / 4)) / 256, 256, 0, stream>>>(OpartT, mpart, lpart, out);
}

// Round 13
// 427.555 us; speedup vs baseline: 1.0832x; 1.0485x over previous
//
#include <hip/hip_runtime.h>
#include <hip/hip_fp16.h>

#define N    8192
#define FIN  256
#define FOUT 128
#define BN   64

typedef _Float16 half8 __attribute__((ext_vector_type(8)));
typedef _Float16 half4v __attribute__((ext_vector_type(4)));
typedef float floatx4 __attribute__((ext_vector_type(4)));

// ---------------------------------------------------------------------------
// W-prep: frag-major fp16 W for coalesced MFMA B-loads.
// ---------------------------------------------------------------------------
__global__ __launch_bounds__(256)
void wprep_kernel(const float* __restrict__ W0,
                  const float* __restrict__ W1,
                  const float* __restrict__ W2,
                  _Float16* __restrict__ Wf)
{
    int idx  = blockIdx.x * 256 + threadIdx.x;   // 0..12287
    int lane = idx & 63;
    int frag = idx >> 6;
    int w    = frag >> 6;
    int f    = frag & 63;
    int nt   = f >> 3, kc = f & 7;
    int quad = lane >> 4, lo16 = lane & 15;
    const float* Wp = w == 0 ? W0 : (w == 1 ? W1 : W2);
    half8 v;
#pragma unroll
    for (int jj = 0; jj < 8; jj++)
        v[jj] = (_Float16)Wp[(size_t)(kc * 32 + quad * 8 + jj) * FOUT + nt * 16 + lo16];
    *(half8*)&Wf[(size_t)idx * 8] = v;
}

// ---------------------------------------------------------------------------
// H = fp16(inp@W), H2 = fp16(inp@W2), H3T = fp16((inp@W3)^T). Barrier-free.
// ---------------------------------------------------------------------------
__global__ __launch_bounds__(256, 2)
void gemm3_kernel(const float* __restrict__ inp,
                  const _Float16* __restrict__ Wf,
                  _Float16* __restrict__ H,
                  _Float16* __restrict__ H2,
                  _Float16* __restrict__ H3T)
{
    const int which = blockIdx.z;
    const int c0    = blockIdx.y * 64;
    const _Float16* Wfw = Wf + (size_t)which * 64 * 64 * 8;
    const int r0 = blockIdx.x * 64;
    const int tid  = threadIdx.x;
    const int wave = tid >> 6;
    const int lane = tid & 63;
    const int lo16 = lane & 15;
    const int quad = lane >> 4;
    const int r = r0 + wave * 16 + lo16;

    half8 a[8];
#pragma unroll
    for (int kc = 0; kc < 8; kc++) {
        const float* p = &inp[(size_t)r * FIN + kc * 32 + quad * 8];
        float4 v0 = *(const float4*)p;
        float4 v1 = *(const float4*)(p + 4);
        a[kc][0] = (_Float16)v0.x; a[kc][1] = (_Float16)v0.y;
        a[kc][2] = (_Float16)v0.z; a[kc][3] = (_Float16)v0.w;
        a[kc][4] = (_Float16)v1.x; a[kc][5] = (_Float16)v1.y;
        a[kc][6] = (_Float16)v1.z; a[kc][7] = (_Float16)v1.w;
    }

    floatx4 acc[4];
#pragma unroll
    for (int i = 0; i < 4; i++) acc[i] = (floatx4){0.f, 0.f, 0.f, 0.f};

#pragma unroll
    for (int kc = 0; kc < 8; kc++)
#pragma unroll
        for (int nt = 0; nt < 4; nt++) {
            int ntg = (c0 >> 4) + nt;
            half8 b = *(const half8*)&Wfw[(((size_t)ntg * 8 + kc) * 64 + lane) * 8];
            acc[nt] = __builtin_amdgcn_mfma_f32_16x16x32_f16(a[kc], b, acc[nt], 0, 0, 0);
        }

    const int arow = wave * 16 + quad * 4;
    if (which < 2) {
        _Float16* outp = which == 0 ? H : H2;
#pragma unroll
        for (int nt = 0; nt < 4; nt++)
#pragma unroll
            for (int rr = 0; rr < 4; rr++)
                outp[(size_t)(r0 + arow + rr) * FOUT + c0 + nt * 16 + lo16] = (_Float16)acc[nt][rr];
    } else {
#pragma unroll
        for (int nt = 0; nt < 4; nt++) {
            half4v v;
#pragma unroll
            for (int rr = 0; rr < 4; rr++) v[rr] = (_Float16)acc[nt][rr];
            *(half4v*)&H3T[(size_t)(c0 + nt * 16 + lo16) * N + r0 + arow] = v;
        }
    }
}

// ---------------------------------------------------------------------------
// Fused repack: blocks [0,512) build Kf (sigma j-permutation baked in),
// blocks [512,1024) build Vf.
// ---------------------------------------------------------------------------
__global__ __launch_bounds__(256)
void repackKV_kernel(const _Float16* __restrict__ H2,
                     const _Float16* __restrict__ H3T,
                     _Float16* __restrict__ Kf,
                     _Float16* __restrict__ Vf)
{
    if (blockIdx.x < 512) {
        int idx  = blockIdx.x * 256 + threadIdx.x;
        int lane = idx & 63;
        int frag = idx >> 6;
        int jb = frag >> 4, f = frag & 15;
        int c = f >> 3, ntj = (f >> 2) & 1, kc = f & 3;
        int quad = lane >> 4, lo16 = lane & 15;
        int srcrow = jb * 64 + c * 32 + (lo16 >> 2) * 8 + ntj * 4 + (lo16 & 3);
        half8 v = *(const half8*)&H2[(size_t)srcrow * FOUT + kc * 32 + quad * 8];
        *(half8*)&Kf[(size_t)idx * 8] = v;
    } else {
        int idx  = (blockIdx.x - 512) * 256 + threadIdx.x;
        int lane = idx & 63;
        int frag = idx >> 6;
        int jb = frag >> 4, f = frag & 15, nt = f >> 1, kc = f & 1;
        int quad = lane >> 4, lo16 = lane & 15;
        half8 v = *(const half8*)&H3T[(size_t)(nt * 16 + lo16) * N + jb * 64 + kc * 32 + quad * 8];
        *(half8*)&Vf[(size_t)idx * 8] = v;
    }
}

// ---------------------------------------------------------------------------
// Flash attention (R9 structure, best measured): S^T formulation, 32 i/wave,
// double-buffered KV LDS, 1 barrier/iter, single-pass 64-j online softmax,
// adj balloted one iteration after issue. Issue order: KV staging regs FIRST,
// then adj (QK's ds_write waits vmcnt(32); adj stays in flight a full iter).
// ---------------------------------------------------------------------------
template<int JS>
__global__ __launch_bounds__(256, 2)
void attn_kernel(const _Float16* __restrict__ Hq,   // [N][128]
                 const _Float16* __restrict__ Kf,   // permuted frag-major
                 const _Float16* __restrict__ Vf,   // frag-major
                 const int* __restrict__ adj,       // [N][N]
                 float* __restrict__ OpartT,        // [JS][FOUT][N]
                 float* __restrict__ mpart,         // [JS][N]
                 float* __restrict__ lpart)         // [JS][N]
{
    __shared__ _Float16 KV[2][16384];   // [buf][16 K frags | 16 V frags]

    const int tid  = threadIdx.x;
    const int wave = tid >> 6;
    const int lane = tid & 63;
    const int lo16 = lane & 15;
    const int quad = lane >> 4;
    const int bid  = blockIdx.x;
    const int js   = bid & (JS - 1);      // XCD affinity
    const int ib   = bid / JS;
    const int iw   = ib * 128 + wave * 32;
    const int jbeg = js * (N / JS);
    const int NIT  = (N / JS) / BN;

    // Q as B-operand fragments for 2 i-subtiles
    half8 q[2][4];
#pragma unroll
    for (int isub = 0; isub < 2; isub++)
#pragma unroll
        for (int kc = 0; kc < 4; kc++)
            q[isub][kc] = *(const half8*)&Hq[(size_t)(iw + isub * 16 + lo16) * FOUT + kc * 32 + quad * 8];

    floatx4 O[8][2];
#pragma unroll
    for (int nt = 0; nt < 8; nt++)
#pragma unroll
        for (int s = 0; s < 2; s++) O[nt][s] = (floatx4){0.f, 0.f, 0.f, 0.f};
    float m_s[2] = {-1e12f, -1e12f}, l_s[2] = {0.f, 0.f};

    // prologue: adj window 0 loads (one iteration of slack before ballot)
    int av[32];
    {
        const int* ap = adj + (size_t)iw * N + jbeg + lane;
#pragma unroll
        for (int x = 0; x < 32; x++) av[x] = ap[(size_t)x * N];
    }

    // prologue: stage KV tile 0 into buf 0
    {
        const int jb0 = jbeg >> 6;
        const _Float16* gk = Kf + (size_t)jb0 * 8192;
        const _Float16* gv = Vf + (size_t)jb0 * 8192;
#pragma unroll
        for (int r = 0; r < 4; r++) {
            int off = (r * 256 + tid) * 8;
            *(half8*)&KV[0][off]        = *(const half8*)&gk[off];
            *(half8*)&KV[0][8192 + off] = *(const half8*)&gv[off];
        }
        __syncthreads();
    }

    int cur = 0;
    for (int it = 0; it < NIT; it++) {
        const int j0 = jbeg + it * BN;

        // ---- 1) ballot the adj window loaded one iteration ago ----
        unsigned long long mw0 = 0, mw1 = 0;
#pragma unroll
        for (int x = 0; x < 16; x++) {
            unsigned long long b0 = __ballot(av[x] != 0);
            unsigned long long b1 = __ballot(av[x + 16] != 0);
            bool sel = (lo16 == x);
            mw0 = sel ? b0 : mw0;
            mw1 = sel ? b1 : mw1;
        }
        unsigned long long mw[2] = {mw0, mw1};

        // ---- 2) prefetch next KV tile into regs (FIRST, so the later
        //         ds_write waits vmcnt(32) and adj stays in flight) ----
        half8 st[8];
        if (it + 1 < NIT) {
            const int jbn = (j0 + BN) >> 6;
            const _Float16* gk = Kf + (size_t)jbn * 8192;
            const _Float16* gv = Vf + (size_t)jbn * 8192;
#pragma unroll
            for (int r = 0; r < 4; r++) {
                int off = (r * 256 + tid) * 8;
                st[r]     = *(const half8*)&gk[off];
                st[r + 4] = *(const half8*)&gv[off];
            }
        }

        // ---- 3) issue adj loads for the NEXT window ----
        if (it + 1 < NIT) {
            const int* ap = adj + (size_t)iw * N + (j0 + BN) + lane;
#pragma unroll
            for (int x = 0; x < 32; x++) av[x] = ap[(size_t)x * N];
        }

        const _Float16* kb = &KV[cur][0];
        const _Float16* vb = &KV[cur][8192];

        // ---- 4) S^T = K Q^T : j = c*32 + 8*quad + 4*ntj + r, i = s*16+lo16
        floatx4 S[2][2][2];   // [c][ntj][isub]
#pragma unroll
        for (int c = 0; c < 2; c++)
#pragma unroll
            for (int ntj = 0; ntj < 2; ntj++) {
                S[c][ntj][0] = (floatx4){0.f, 0.f, 0.f, 0.f};
                S[c][ntj][1] = (floatx4){0.f, 0.f, 0.f, 0.f};
#pragma unroll
                for (int kc = 0; kc < 4; kc++) {
                    half8 kf = *(const half8*)&kb[(((c * 2 + ntj) * 4 + kc) * 64 + lane) * 8];
                    S[c][ntj][0] = __builtin_amdgcn_mfma_f32_16x16x32_f16(kf, q[0][kc], S[c][ntj][0], 0, 0, 0);
                    S[c][ntj][1] = __builtin_amdgcn_mfma_f32_16x16x32_f16(kf, q[1][kc], S[c][ntj][1], 0, 0, 0);
                }
            }

        // ---- 5) single-pass online softmax over the 64-j window ----
        float alpha[2];
#pragma unroll
        for (int s = 0; s < 2; s++) {
            float mx = -1e12f;
#pragma unroll
            for (int c = 0; c < 2; c++)
#pragma unroll
                for (int ntj = 0; ntj < 2; ntj++)
#pragma unroll
                    for (int r = 0; r < 4; r++) {
                        float e = S[c][ntj][s][r];
                        e = e > 0.f ? e : 0.2f * e;
                        mx = fmaxf(mx, e);
                    }
            mx = fmaxf(mx, __shfl_xor(mx, 16));
            mx = fmaxf(mx, __shfl_xor(mx, 32));
            float mn = fmaxf(m_s[s], mx);
            alpha[s] = __expf(m_s[s] - mn);
            m_s[s] = mn;
        }

        half8 pb[2][2];       // [isub][c], element jj = 4*ntj + r
        float sum[2] = {0.f, 0.f};
#pragma unroll
        for (int s = 0; s < 2; s++) {
            unsigned long long mq = mw[s] >> (quad * 8);
#pragma unroll
            for (int c = 0; c < 2; c++)
#pragma unroll
                for (int ntj = 0; ntj < 2; ntj++)
#pragma unroll
                    for (int r = 0; r < 4; r++) {
                        float e = S[c][ntj][s][r];
                        e = e > 0.f ? e : 0.2f * e;
                        bool bit = (mq >> (c * 32 + ntj * 4 + r)) & 1ull;
                        float p = bit ? __expf(e - m_s[s]) : 0.f;
                        sum[s] += p;
                        pb[s][c][ntj * 4 + r] = (_Float16)p;
                    }
            sum[s] += __shfl_xor(sum[s], 16);
            sum[s] += __shfl_xor(sum[s], 32);
            l_s[s] = l_s[s] * alpha[s] + sum[s];
#pragma unroll
            for (int nt = 0; nt < 8; nt++)
#pragma unroll
                for (int r = 0; r < 4; r++)
                    O[nt][s][r] *= alpha[s];
        }

        // ---- 6) O^T += V^T P^T ----
#pragma unroll
        for (int c = 0; c < 2; c++)
#pragma unroll
            for (int nt = 0; nt < 8; nt++) {
                half8 vf = *(const half8*)&vb[((nt * 2 + c) * 64 + lane) * 8];
                O[nt][0] = __builtin_amdgcn_mfma_f32_16x16x32_f16(vf, pb[0][c], O[nt][0], 0, 0, 0);
                O[nt][1] = __builtin_amdgcn_mfma_f32_16x16x32_f16(vf, pb[1][c], O[nt][1], 0, 0, 0);
            }

        // ---- 7) commit prefetched KV tile; one barrier per iter ----
        if (it + 1 < NIT) {
            const int nxt = cur ^ 1;
#pragma unroll
            for (int r = 0; r < 4; r++) {
                int off = (r * 256 + tid) * 8;
                *(half8*)&KV[nxt][off]        = st[r];
                *(half8*)&KV[nxt][8192 + off] = st[r + 4];
            }
        }
        __syncthreads();
        cur ^= 1;
    }

    // epilogue: O^T[f][i] -> OpartT[js][f][i] (unnormalized) + (m,l)
#pragma unroll
    for (int nt = 0; nt < 8; nt++)
#pragma unroll
        for (int s = 0; s < 2; s++)
#pragma unroll
            for (int r = 0; r < 4; r++) {
                int f = nt * 16 + quad * 4 + r;
                int i = iw + s * 16 + lo16;
                OpartT[((size_t)js * FOUT + f) * N + i] = O[nt][s][r];
            }
    if (quad == 0) {
#pragma unroll
        for (int s = 0; s < 2; s++) {
            mpart[js * N + iw + s * 16 + lo16] = m_s[s];
            lpart[js * N + iw + s * 16 + lo16] = l_s[s];
        }
    }
}

// ---------------------------------------------------------------------------
// Combine: f-major partials -> normalize -> ELU -> out[i][f].
// ---------------------------------------------------------------------------
template<int JS>
__global__ __launch_bounds__(256)
void combine_kernel(const float* __restrict__ OpartT,
                    const float* __restrict__ mpart,
                    const float* __restrict__ lpart,
                    float* __restrict__ out)
{
    int idx = blockIdx.x * 256 + threadIdx.x;   // 128 f x 2048 i-groups
    int f  = idx >> 11;
    int i4 = (idx & 2047) << 2;

    float4 M = {-3e38f, -3e38f, -3e38f, -3e38f};
    float4 m[JS];
#pragma unroll
    for (int s = 0; s < JS; s++) {
        m[s] = *(const float4*)&mpart[s * N + i4];
        M.x = fmaxf(M.x, m[s].x); M.y = fmaxf(M.y, m[s].y);
        M.z = fmaxf(M.z, m[s].z); M.w = fmaxf(M.w, m[s].w);
    }
    float4 L = {0.f, 0.f, 0.f, 0.f};
    float4 w[JS];
#pragma unroll
    for (int s = 0; s < JS; s++) {
        float4 l = *(const float4*)&lpart[s * N + i4];
        w[s].x = __expf(m[s].x - M.x); w[s].y = __expf(m[s].y - M.y);
        w[s].z = __expf(m[s].z - M.z); w[s].w = __expf(m[s].w - M.w);
        L.x += l.x * w[s].x; L.y += l.y * w[s].y;
        L.z += l.z * w[s].z; L.w += l.w * w[s].w;
    }
    float4 o = {0.f, 0.f, 0.f, 0.f};
#pragma unroll
    for (int s = 0; s < JS; s++) {
        float4 v = *(const float4*)&OpartT[((size_t)s * FOUT + f) * N + i4];
        o.x += w[s].x * v.x; o.y += w[s].y * v.y;
        o.z += w[s].z * v.z; o.w += w[s].w * v.w;
    }
    float r0 = o.x / L.x, r1 = o.y / L.y, r2 = o.z / L.z, r3 = o.w / L.w;
    out[(size_t)(i4 + 0) * FOUT + f] = r0 > 0.f ? r0 : __expf(r0) - 1.f;
    out[(size_t)(i4 + 1) * FOUT + f] = r1 > 0.f ? r1 : __expf(r1) - 1.f;
    out[(size_t)(i4 + 2) * FOUT + f] = r2 > 0.f ? r2 : __expf(r2) - 1.f;
    out[(size_t)(i4 + 3) * FOUT + f] = r3 > 0.f ? r3 : __expf(r3) - 1.f;
}

// ---------------------------------------------------------------------------
extern "C" void kernel_launch(void* const* d_in, const int* in_sizes, int n_in,
                              void* d_out, int out_size, void* d_ws, size_t ws_size,
                              hipStream_t stream) {
    const float* inp = (const float*)d_in[0];
    const int*   adj = (const int*)d_in[1];
    const float* W0  = (const float*)d_in[2];
    const float* W1  = (const float*)d_in[3];
    const float* W2  = (const float*)d_in[4];
    float* out = (float*)d_out;

    constexpr int JS = 8;
    char* ws = (char*)d_ws;
    _Float16* H    = (_Float16*)(ws);                          // 2 MB
    _Float16* H2   = (_Float16*)(ws + (2u << 20));             // 2 MB
    _Float16* H3T  = (_Float16*)(ws + (4u << 20));             // 2 MB
    _Float16* Wf   = (_Float16*)(ws + (6u << 20));             // 192 KB
    _Float16* Kf   = (_Float16*)(ws + (7u << 20));             // 2 MB
    _Float16* Vf   = (_Float16*)(ws + (9u << 20));             // 2 MB
    float* OpartT  = (float*)(ws + (11u << 20));               // 32 MB
    float* mpart   = (float*)(ws + (43u << 20));               // 256 KB
    float* lpart   = (float*)(ws + (43u << 20) + (size_t)JS * N * sizeof(float));

    wprep_kernel<<<48, 256, 0, stream>>>(W0, W1, W2, Wf);
    gemm3_kernel<<<dim3(N / 64, 2, 3), 256, 0, stream>>>(inp, Wf, H, H2, H3T);
    repackKV_kernel<<<1024, 256, 0, stream>>>(H2, H3T, Kf, Vf);
    attn_kernel<JS><<<(N / 128) * JS, 256, 0, stream>>>(H, Kf, Vf, adj, OpartT, mpart, lpart);
    combine_kernel<JS><<<(FOUT * (N / 4)) / 256, 256, 0, stream>>>(OpartT, mpart, lpart, out);
}